// Round 2
// baseline (5505.114 us; speedup 1.0000x reference)
//
#include <hip/hip_runtime.h>
#include <stdint.h>

// ---------------- problem constants ----------------
#define Bc 128
#define Tc 1024
#define Fc 64
#define Hc 256

typedef float f32x4 __attribute__((ext_vector_type(4)));
typedef short s16x8 __attribute__((ext_vector_type(8)));

#define MFMA16(a, b, c) __builtin_amdgcn_mfma_f32_16x16x32_bf16((a), (b), (c), 0, 0, 0)

// Static exchange buffer: 2 parity slots x [B][H] tagged 64-bit words.
// .bss -> zero-initialized at load; tag 0 is never consumed, and the kernel's
// final handshake+scrub restores a safe state for back-to-back replays.
__device__ unsigned long long g_hbuf[2 * Bc * Hc];

__device__ __forceinline__ unsigned short f2bf(float f) {
  unsigned u = __float_as_uint(f);
  u += 0x7FFFu + ((u >> 16) & 1u);
  return (unsigned short)(u >> 16);
}
__device__ __forceinline__ float bf2f(unsigned short h) {
  return __uint_as_float(((unsigned)h) << 16);
}
__device__ __forceinline__ float sigm(float x) { return 1.0f / (1.0f + __expf(-x)); }
__device__ __forceinline__ float tanh2(float x) { return 1.0f - 2.0f / (__expf(2.0f * x) + 1.0f); }

__device__ __forceinline__ void wfrag2(const float* p, s16x8& hi, s16x8& lo) {
#pragma unroll
  for (int j = 0; j < 8; ++j) {
    unsigned short h = f2bf(p[j]);
    hi[j] = (short)h;
    lo[j] = (short)f2bf(p[j] - bf2f(h));
  }
}
__device__ __forceinline__ void wfrag2sum(const float* p, const float* q, s16x8& hi, s16x8& lo) {
#pragma unroll
  for (int j = 0; j < 8; ++j) {
    float v = p[j] + q[j];
    unsigned short h = f2bf(v);
    hi[j] = (short)h;
    lo[j] = (short)f2bf(v - bf2f(h));
  }
}
__device__ __forceinline__ f32x4 splat4(float v) {
  f32x4 r; r[0] = v; r[1] = v; r[2] = v; r[3] = v; return r;
}

// Persistent VRAE kernel.
// Grid: 64 WGs x 256 threads. sg = blockIdx&7 (sample group of 16; same XCD under
// round-robin block->XCD), gg = blockIdx>>3 (column group of 32 h-cols).
// Each WG owns gate rows {gt*256 + gg*32 .. +32} for gt in {i,f,g,o} -> c/h update is WG-local.
// h exchange: tagged 64-bit words, tag = step id (high 32b), payload = bf16 hi/lo split of h.
extern "C" __global__ void __launch_bounds__(256, 1)
vrae_persistent(const float* __restrict__ x, const float* __restrict__ eps,
                const float* __restrict__ Wih_e, const float* __restrict__ Whh_e,
                const float* __restrict__ b_e,
                const float* __restrict__ Wmp, const float* __restrict__ bmp,
                const float* __restrict__ Wlp, const float* __restrict__ blp,
                const float* __restrict__ Wih_d, const float* __restrict__ Whh_d,
                const float* __restrict__ b_d,
                const float* __restrict__ Wmx, const float* __restrict__ bmx,
                const float* __restrict__ Wlx, const float* __restrict__ blx,
                float* __restrict__ out)
{
  __shared__ unsigned short h_hi[16][264];  // stride 264*2B = 33*16B: 16B-aligned rows
  __shared__ unsigned short h_lo[16][264];
  __shared__ unsigned short x_hi[16][72];
  __shared__ unsigned short x_lo[16][72];
  __shared__ float glds[4][16][36];         // [gate type][sample][local col]

  unsigned long long* hbuf = g_hbuf;

  const int tid  = threadIdx.x;
  const int wg   = blockIdx.x;
  const int sg   = wg & 7;           // sample group 0..7 (samples [16sg, 16sg+16))
  const int gg   = wg >> 3;          // column group 0..7 (h cols [32gg, 32gg+32))
  const int wv   = tid >> 6;         // wave 0..3 == gate type i/f/g/o
  const int l15  = tid & 15;         // lane & 15 (waves are 64-aligned)
  const int quad = (tid >> 4) & 3;   // lane >> 4
  const int s0   = sg * 16;
  const int um   = tid >> 4;         // update mapping: sample 0..15
  const int uj   = tid & 15;         // update mapping: col-low 0..15

  // ---- tagged h exchange helpers ----
  auto consume = [&](int tag) {
    const unsigned long long* src =
        hbuf + (size_t)(tag & 1) * (Bc * Hc) + (size_t)(s0 + um) * Hc;
    unsigned long long w[16];
#pragma unroll
    for (int u = 0; u < 16; ++u)
      w[u] = __hip_atomic_load(src + uj + 16 * u, __ATOMIC_RELAXED, __HIP_MEMORY_SCOPE_AGENT);
    for (;;) {
      bool ok = true;
#pragma unroll
      for (int u = 0; u < 16; ++u) ok = ok && ((w[u] >> 32) == (unsigned long long)(unsigned)tag);
      if (ok) break;
      __builtin_amdgcn_s_sleep(2);
#pragma unroll
      for (int u = 0; u < 16; ++u)
        if ((w[u] >> 32) != (unsigned long long)(unsigned)tag)
          w[u] = __hip_atomic_load(src + uj + 16 * u, __ATOMIC_RELAXED, __HIP_MEMORY_SCOPE_AGENT);
    }
#pragma unroll
    for (int u = 0; u < 16; ++u) {
      h_hi[um][uj + 16 * u] = (unsigned short)(w[u] >> 16);
      h_lo[um][uj + 16 * u] = (unsigned short)(w[u] & 0xFFFFu);
    }
  };

  auto publish_h = [&](int otag, float hv, int jloc) {
    unsigned long long* dst =
        hbuf + (size_t)(otag & 1) * (Bc * Hc) + (size_t)(s0 + um) * Hc + gg * 32 + jloc;
    unsigned short hi = f2bf(hv);
    unsigned short lo = f2bf(hv - bf2f(hi));
    unsigned long long word = ((unsigned long long)(unsigned)otag << 32) |
                              (((unsigned)hi << 16) | (unsigned)lo);
    __hip_atomic_store(dst, word, __ATOMIC_RELAXED, __HIP_MEMORY_SCOPE_AGENT);
  };

  float creg0 = 0.f, creg1 = 0.f;  // cell state for local cols uj, uj+16 of sample um
  auto lstm_update = [&](int otag) {
#pragma unroll
    for (int u = 0; u < 2; ++u) {
      const int j = uj + 16 * u;
      float gi = glds[0][um][j], gf = glds[1][um][j];
      float gc = glds[2][um][j], go = glds[3][um][j];
      float iv = sigm(gi), fv = sigm(gf), cv = tanh2(gc), ov = sigm(go);
      float cr = u ? creg1 : creg0;
      cr = fv * cr + iv * cv;
      float hv = ov * tanh2(cr);
      if (u) creg1 = cr; else creg0 = cr;
      publish_h(otag, hv, j);
    }
  };

  // ---- encoder weight fragments (persistent in VGPRs, bf16 hi/lo split) ----
  s16x8 wmh[2][8], wml[2][8];  // recurrent weights (enc Whh, later dec Wih+Whh)
  s16x8 wxh[2][2], wxl[2][2];  // enc Wih
  float biasg[2];
#pragma unroll
  for (int ch = 0; ch < 2; ++ch) {
    const int row = wv * 256 + gg * 32 + ch * 16 + l15;  // B-frag col n = l15
    biasg[ch] = b_e[row];
#pragma unroll
    for (int c = 0; c < 8; ++c)
      wfrag2(Whh_e + (size_t)row * Hc + c * 32 + quad * 8, wmh[ch][c], wml[ch][c]);
#pragma unroll
    for (int c = 0; c < 2; ++c)
      wfrag2(Wih_e + (size_t)row * Fc + c * 32 + quad * 8, wxh[ch][c], wxl[ch][c]);
  }

  // zero initial hidden state
#pragma unroll
  for (int u = 0; u < 16; ++u) { h_hi[um][uj + 16 * u] = 0; h_lo[um][uj + 16 * u] = 0; }
  __syncthreads();

  // =================== encoder: 1024 steps ===================
  for (int it = 0; it < Tc; ++it) {
    {  // stage x_t into LDS (bf16 hi/lo)
      const float* xp = x + (size_t)(s0 + um) * (Tc * Fc) + (size_t)it * Fc + uj * 4;
      f32x4 xv = *(const f32x4*)xp;
#pragma unroll
      for (int j = 0; j < 4; ++j) {
        unsigned short h = f2bf(xv[j]);
        x_hi[um][uj * 4 + j] = h;
        x_lo[um][uj * 4 + j] = f2bf(xv[j] - bf2f(h));
      }
    }
    if (it > 0) consume(it);
    __syncthreads();

    f32x4 acc0 = splat4(biasg[0]);
    f32x4 acc1 = splat4(biasg[1]);
#pragma unroll
    for (int c = 0; c < 2; ++c) {  // x @ Wih^T
      s16x8 ah = *(const s16x8*)&x_hi[l15][c * 32 + quad * 8];
      s16x8 al = *(const s16x8*)&x_lo[l15][c * 32 + quad * 8];
      acc0 = MFMA16(ah, wxh[0][c], acc0);
      acc0 = MFMA16(ah, wxl[0][c], acc0);
      acc0 = MFMA16(al, wxh[0][c], acc0);
      acc1 = MFMA16(ah, wxh[1][c], acc1);
      acc1 = MFMA16(ah, wxl[1][c], acc1);
      acc1 = MFMA16(al, wxh[1][c], acc1);
    }
#pragma unroll
    for (int c = 0; c < 8; ++c) {  // h @ Whh^T
      s16x8 ah = *(const s16x8*)&h_hi[l15][c * 32 + quad * 8];
      s16x8 al = *(const s16x8*)&h_lo[l15][c * 32 + quad * 8];
      acc0 = MFMA16(ah, wmh[0][c], acc0);
      acc0 = MFMA16(ah, wml[0][c], acc0);
      acc0 = MFMA16(al, wmh[0][c], acc0);
      acc1 = MFMA16(ah, wmh[1][c], acc1);
      acc1 = MFMA16(ah, wml[1][c], acc1);
      acc1 = MFMA16(al, wmh[1][c], acc1);
    }
#pragma unroll
    for (int r = 0; r < 4; ++r) {  // D: row(sample)=quad*4+r, col=l15
      glds[wv][quad * 4 + r][l15]      = acc0[r];
      glds[wv][quad * 4 + r][16 + l15] = acc1[r];
    }
    __syncthreads();
    lstm_update(it + 1);
  }

  // =================== posterior heads + reparameterization ===================
  consume(Tc);  // h_T
  {
    const float* WM = (wv < 2) ? Wmp : Wlp;
    const float* bM = (wv < 2) ? bmp : blp;
    const int prow = gg * 32 + (wv & 1) * 16 + l15;
    s16x8 wph[8], wpl[8];
#pragma unroll
    for (int c = 0; c < 8; ++c)
      wfrag2(WM + (size_t)prow * Hc + c * 32 + quad * 8, wph[c], wpl[c]);
    const float pb = bM[prow];
    __syncthreads();
    f32x4 acc = splat4(pb);
#pragma unroll
    for (int c = 0; c < 8; ++c) {
      s16x8 ah = *(const s16x8*)&h_hi[l15][c * 32 + quad * 8];
      s16x8 al = *(const s16x8*)&h_lo[l15][c * 32 + quad * 8];
      acc = MFMA16(ah, wph[c], acc);
      acc = MFMA16(ah, wpl[c], acc);
      acc = MFMA16(al, wph[c], acc);
    }
#pragma unroll
    for (int r = 0; r < 4; ++r)
      glds[wv >> 1][quad * 4 + r][(wv & 1) * 16 + l15] = acc[r];
    __syncthreads();
#pragma unroll
    for (int u = 0; u < 2; ++u) {
      const int j  = uj + 16 * u;
      const int jg = gg * 32 + j;
      float mu = glds[0][um][j];
      float lp = glds[1][um][j];
      float ev = eps[(size_t)(s0 + um) * Hc + jg];
      float z  = ev * __expf(0.5f * lp) + mu;
      out[(size_t)(s0 + um) * Hc + jg] = mu;
      out[(size_t)Bc * Hc + (size_t)(s0 + um) * Hc + jg] = lp;
      publish_h(Tc + 1, z, j);  // z0 becomes decoder h_0
    }
    creg0 = 0.f; creg1 = 0.f;
  }

  // ---- decoder weight fragments: Wsum = Wih_d + Whh_d (y_t == h_t for t>=1) ----
#pragma unroll
  for (int ch = 0; ch < 2; ++ch) {
    const int row = wv * 256 + gg * 32 + ch * 16 + l15;
    biasg[ch] = b_d[row];
#pragma unroll
    for (int c = 0; c < 8; ++c)
      wfrag2sum(Wih_d + (size_t)row * Hc + c * 32 + quad * 8,
                Whh_d + (size_t)row * Hc + c * 32 + quad * 8,
                wmh[ch][c], wml[ch][c]);
  }
  s16x8 wpjh[8], wpjl[8];  // output projection slice (16 cols of W_mx or W_lx), wave 0
  float pjb;
  {
    const float* WP = (gg < 4) ? Wmx : Wlx;
    const float* bP = (gg < 4) ? bmx : blx;
    const int prow = (gg & 3) * 16 + l15;
    pjb = bP[prow];
#pragma unroll
    for (int c = 0; c < 8; ++c)
      wfrag2(WP + (size_t)prow * Hc + c * 32 + quad * 8, wpjh[c], wpjl[c]);
  }
  const size_t outMu = (size_t)2 * Bc * Hc;
  const size_t outLs = outMu + (size_t)Bc * Tc * Fc;

  // =================== decoder: 1024 steps (+1 trailing projection) ===================
  for (int it = 0; it <= Tc; ++it) {
    consume(Tc + 1 + it);  // h_dec_it (it==0 -> z0)
    __syncthreads();

    if (it < Tc) {
      f32x4 acc0 = splat4(biasg[0]);
      f32x4 acc1 = splat4(biasg[1]);
      if (it == 0) {
        // step 0: y=0 -> gates = Whh_d * z0 + b (one-time, frags loaded on the fly)
#pragma unroll
        for (int ch = 0; ch < 2; ++ch) {
          const int row = wv * 256 + gg * 32 + ch * 16 + l15;
#pragma unroll
          for (int c = 0; c < 8; ++c) {
            s16x8 wzh, wzl;
            wfrag2(Whh_d + (size_t)row * Hc + c * 32 + quad * 8, wzh, wzl);
            s16x8 ah = *(const s16x8*)&h_hi[l15][c * 32 + quad * 8];
            s16x8 al = *(const s16x8*)&h_lo[l15][c * 32 + quad * 8];
            f32x4& acc = ch ? acc1 : acc0;
            acc = MFMA16(ah, wzh, acc);
            acc = MFMA16(ah, wzl, acc);
            acc = MFMA16(al, wzh, acc);
          }
        }
      } else {
#pragma unroll
        for (int c = 0; c < 8; ++c) {
          s16x8 ah = *(const s16x8*)&h_hi[l15][c * 32 + quad * 8];
          s16x8 al = *(const s16x8*)&h_lo[l15][c * 32 + quad * 8];
          acc0 = MFMA16(ah, wmh[0][c], acc0);
          acc0 = MFMA16(ah, wml[0][c], acc0);
          acc0 = MFMA16(al, wmh[0][c], acc0);
          acc1 = MFMA16(ah, wmh[1][c], acc1);
          acc1 = MFMA16(ah, wml[1][c], acc1);
          acc1 = MFMA16(al, wmh[1][c], acc1);
        }
      }
#pragma unroll
      for (int r = 0; r < 4; ++r) {
        glds[wv][quad * 4 + r][l15]      = acc0[r];
        glds[wv][quad * 4 + r][16 + l15] = acc1[r];
      }
      __syncthreads();
      lstm_update(Tc + 2 + it);  // publish h_dec_{it+1} ASAP (projection off critical path)
    }

    // output projection of h_dec_it == ys[it-1] (wave 0; 16 cols of mu_xhat or ls_xhat)
    if (it > 0 && wv == 0) {
      f32x4 acc = splat4(pjb);
#pragma unroll
      for (int c = 0; c < 8; ++c) {
        s16x8 ah = *(const s16x8*)&h_hi[l15][c * 32 + quad * 8];
        s16x8 al = *(const s16x8*)&h_lo[l15][c * 32 + quad * 8];
        acc = MFMA16(ah, wpjh[c], acc);
        acc = MFMA16(ah, wpjl[c], acc);
        acc = MFMA16(al, wpjh[c], acc);
      }
      const size_t base = (gg < 4) ? outMu : outLs;
      const int tout = it - 1;
      const int fcol = (gg & 3) * 16 + l15;
#pragma unroll
      for (int r = 0; r < 4; ++r) {
        const int m = quad * 4 + r;
        out[base + ((size_t)(s0 + m) * Tc + tout) * Fc + fcol] = acc[r];
      }
    }
    __syncthreads();  // h LDS stable until everyone finished projection
  }

  // ---- final handshake (tag 2050, parity 0) then scrub odd-parity words so that
  // back-to-back replays can never see a stale matching tag ----
  {
    const int atag = 2 * Tc + 2;  // 2050, parity 0
#pragma unroll
    for (int u = 0; u < 2; ++u) {
      unsigned long long* dst = hbuf + (size_t)(s0 + um) * Hc + gg * 32 + uj + 16 * u;
      __hip_atomic_store(dst, ((unsigned long long)(unsigned)atag << 32),
                         __ATOMIC_RELAXED, __HIP_MEMORY_SCOPE_AGENT);
    }
    consume(atag);  // everyone in the sample group is done with parity-1 data
#pragma unroll
    for (int u = 0; u < 2; ++u) {
      unsigned long long* dst =
          hbuf + (size_t)(Bc * Hc) + (size_t)(s0 + um) * Hc + gg * 32 + uj + 16 * u;
      __hip_atomic_store(dst, 0ull, __ATOMIC_RELAXED, __HIP_MEMORY_SCOPE_AGENT);
    }
  }
}

extern "C" void kernel_launch(void* const* d_in, const int* in_sizes, int n_in,
                              void* d_out, int out_size, void* d_ws, size_t ws_size,
                              hipStream_t stream)
{
  (void)in_sizes; (void)n_in; (void)out_size; (void)d_ws; (void)ws_size;

  const float* x     = (const float*)d_in[0];
  const float* eps   = (const float*)d_in[1];
  const float* Wih_e = (const float*)d_in[2];
  const float* Whh_e = (const float*)d_in[3];
  const float* b_e   = (const float*)d_in[4];
  const float* Wmp   = (const float*)d_in[5];
  const float* bmp   = (const float*)d_in[6];
  const float* Wlp   = (const float*)d_in[7];
  const float* blp   = (const float*)d_in[8];
  const float* Wih_d = (const float*)d_in[9];
  const float* Whh_d = (const float*)d_in[10];
  const float* b_d   = (const float*)d_in[11];
  const float* Wmx   = (const float*)d_in[12];
  const float* bmx   = (const float*)d_in[13];
  const float* Wlx   = (const float*)d_in[14];
  const float* blx   = (const float*)d_in[15];
  float* out = (float*)d_out;

  void* args[] = { &x, &eps, &Wih_e, &Whh_e, &b_e, &Wmp, &bmp, &Wlp, &blp,
                   &Wih_d, &Whh_d, &b_d, &Wmx, &bmx, &Wlx, &blx, &out };
  hipError_t err = hipLaunchCooperativeKernel((void*)vrae_persistent, dim3(64), dim3(256),
                                              args, 0, stream);
  if (err != hipSuccess) {
    // 64 blocks at 1 block/CU on a 256-CU device are trivially co-resident;
    // the tagged-exchange protocol needs only co-residency, not grid sync.
    vrae_persistent<<<dim3(64), dim3(256), 0, stream>>>(
        x, eps, Wih_e, Whh_e, b_e, Wmp, bmp, Wlp, blp,
        Wih_d, Whh_d, b_d, Wmx, bmx, Wlx, blx, out);
  }
}